// Round 18
// baseline (442.370 us; speedup 1.0000x reference)
//
#include <hip/hip_runtime.h>
#include <math.h>

#define NB 8          // batch
#define NC 3          // channels
#define PD 192        // feature dim = 3*8*8
#define IMG 512
#define NP 169        // patches per spatial dim
#define NPATCH 28561  // NP*NP
#define INV_N (1.0f/28561.0f)
#define KST 32        // GEMM K-step (patches per MFMA tile)

typedef float f4 __attribute__((ext_vector_type(4)));
typedef __bf16 bf16x8 __attribute__((ext_vector_type(8)));
typedef float f32x4 __attribute__((ext_vector_type(4)));

__device__ __forceinline__ float rdlane(float v, int lane) {
  return __uint_as_float(__builtin_amdgcn_readlane(__float_as_uint(v), lane));
}

// DPP-based add of a shifted copy (VALU, no LDS pipe).
template<int CTRL, int RM, int BM>
__device__ __forceinline__ float dpp_add(float x) {
  int sh = __builtin_amdgcn_update_dpp(0, __float_as_int(x), CTRL, RM, BM, false);
  return x + __int_as_float(sh);
}
// sum over all 64 lanes -> scalar (uniform)
__device__ __forceinline__ float wave_sum(float x) {
  x = dpp_add<0x111, 0xF, 0xF>(x);   // row_shr:1
  x = dpp_add<0x112, 0xF, 0xF>(x);   // row_shr:2
  x = dpp_add<0x114, 0xF, 0xF>(x);   // row_shr:4
  x = dpp_add<0x118, 0xF, 0xF>(x);   // row_shr:8
  x = dpp_add<0x142, 0xA, 0xF>(x);   // row_bcast:15 -> rows 1,3
  x = dpp_add<0x143, 0xC, 0xF>(x);   // row_bcast:31 -> rows 2,3
  return rdlane(x, 63);
}
// sum over lanes 0..15 (replicated per 16-group) -> scalar
__device__ __forceinline__ float row16_sum(float x) {
  x = dpp_add<0x111, 0xF, 0xF>(x);
  x = dpp_add<0x112, 0xF, 0xF>(x);
  x = dpp_add<0x114, 0xF, 0xF>(x);
  x = dpp_add<0x118, 0xF, 0xF>(x);
  return rdlane(x, 15);
}

// RNE float->bf16 bits
__device__ __forceinline__ unsigned bfh(float v) {
  unsigned u = __float_as_uint(v);
  return (u + 0x7FFFu + ((u >> 16) & 1u)) >> 16;
}

// ---------------- split-K Gram via bf16-split MFMA + fused feature sums ----------------
__global__ __launch_bounds__(512) void cov_gemm_k(const float* __restrict__ x,
                                                  float* __restrict__ partial,
                                                  float* __restrict__ Spart,
                                                  int CH, int chunkSize) {
  int chunk = blockIdx.x % CH;
  int b = blockIdx.x / CH;
  int p0 = chunk * chunkSize;
  int pcount = NPATCH - p0;
  if (pcount > chunkSize) pcount = chunkSize;
  if (pcount < 0) pcount = 0;
  int nkt = (pcount + KST - 1) / KST;
  int pend = p0 + pcount;

  __shared__ unsigned short hiT[PD * 40];   // row stride 40 ushorts = 80B
  __shared__ unsigned short loT[PD * 40];
  __shared__ float sred[PD * 16];           // feature-sum reduce buffer

  int t = threadIdx.x;
  int l = t & 63, w = t >> 6;
  int wr = w >> 2, wc = w & 3;
  int m0 = wr * 96, n0 = wc * 48;
  const float* imgb = x + (size_t)b * NC * IMG * IMG;

  f32x4 acc[6][3];
#pragma unroll
  for (int i = 0; i < 6; ++i)
#pragma unroll
    for (int j = 0; j < 3; ++j)
      acc[i][j] = (f32x4){0.f, 0.f, 0.f, 0.f};

  float fsum[6] = {0.f, 0.f, 0.f, 0.f, 0.f, 0.f};

  int krow = (l >> 4) << 3;   // ushort k-offset: 0,8,16,24
  int rsel = l & 15;

  for (int kt = 0; kt < nkt; ++kt) {
    int pbase = p0 + kt * KST;
#pragma unroll
    for (int s = 0; s < 6; ++s) {
      int idx = (s << 9) + t;          // 0..3071
      int f = idx >> 4, p2 = idx & 15;
      int c = f >> 6, ii = (f >> 3) & 7, jj = f & 7;
      const float* imgc = imgb + (size_t)c * IMG * IMG;
      int P0 = pbase + (p2 << 1);
      float v0 = 0.f, v1 = 0.f;
      if (P0 < pend) { int ph = P0 / NP, pw = P0 - ph * NP; v0 = imgc[(3 * ph + ii) * IMG + 3 * pw + jj]; }
      if (P0 + 1 < pend) { int ph = (P0 + 1) / NP, pw = (P0 + 1) - ph * NP; v1 = imgc[(3 * ph + ii) * IMG + 3 * pw + jj]; }
      fsum[s] += v0 + v1;
      unsigned h0 = bfh(v0), h1 = bfh(v1);
      float r0 = v0 - __uint_as_float(h0 << 16);
      float r1 = v1 - __uint_as_float(h1 << 16);
      unsigned g0 = bfh(r0), g1 = bfh(r1);
      *(unsigned*)&hiT[f * 40 + (p2 << 1)] = h0 | (h1 << 16);
      *(unsigned*)&loT[f * 40 + (p2 << 1)] = g0 | (g1 << 16);
    }
    __syncthreads();

    bf16x8 ah[6], al[6], bh[3], bl[3];
#pragma unroll
    for (int i = 0; i < 6; ++i) {
      int row = m0 + i * 16 + rsel;
      ah[i] = *(const bf16x8*)&hiT[row * 40 + krow];
      al[i] = *(const bf16x8*)&loT[row * 40 + krow];
    }
#pragma unroll
    for (int j = 0; j < 3; ++j) {
      int row = n0 + j * 16 + rsel;
      bh[j] = *(const bf16x8*)&hiT[row * 40 + krow];
      bl[j] = *(const bf16x8*)&loT[row * 40 + krow];
    }
#pragma unroll
    for (int i = 0; i < 6; ++i)
#pragma unroll
      for (int j = 0; j < 3; ++j) {
        acc[i][j] = __builtin_amdgcn_mfma_f32_16x16x32_bf16(ah[i], bh[j], acc[i][j], 0, 0, 0);
        acc[i][j] = __builtin_amdgcn_mfma_f32_16x16x32_bf16(ah[i], bl[j], acc[i][j], 0, 0, 0);
        acc[i][j] = __builtin_amdgcn_mfma_f32_16x16x32_bf16(al[i], bh[j], acc[i][j], 0, 0, 0);
      }
    __syncthreads();
  }

  // ---- feature-sum reduce: sred[f][p2] -> Spart ----
#pragma unroll
  for (int s = 0; s < 6; ++s) {
    int f = (t >> 4) + (s << 5);
    sred[(f << 4) | (t & 15)] = fsum[s];
  }
  __syncthreads();
  if (t < PD) {
    float s = 0.f;
#pragma unroll
    for (int p2 = 0; p2 < 16; ++p2) s += sred[(t << 4) | p2];
    Spart[((size_t)chunk * NB + b) * PD + t] = s;
  }

  float* outp = partial + ((size_t)chunk * NB + b) * PD * PD;
#pragma unroll
  for (int i = 0; i < 6; ++i) {
    int rowb = m0 + i * 16 + ((l >> 4) << 2);
#pragma unroll
    for (int r = 0; r < 4; ++r)
#pragma unroll
      for (int j = 0; j < 3; ++j)
        outp[(size_t)(rowb + r) * PD + n0 + j * 16 + (l & 15)] = acc[i][j][r];
  }
}

// ---------------- sum per-chunk feature sums -> S ----------------
__global__ __launch_bounds__(192) void musum_k(const float* __restrict__ Spart,
                                               float* __restrict__ S, int CH) {
  int b = blockIdx.x, t = threadIdx.x;
  float s = 0.f;
  for (int c = 0; c < CH; ++c) s += Spart[((size_t)c * NB + b) * PD + t];
  S[b * PD + t] = s;
}

// ---------------- reduce partials + finalize covariance ----------------
__global__ __launch_bounds__(256) void reduce_fin_k(const float* __restrict__ partial,
                                                    const float* __restrict__ S,
                                                    float* __restrict__ G, int CH) {
  int e = blockIdx.x * 256 + threadIdx.x;
  const int tot = NB * PD * PD;
  if (e >= tot) return;
  int b = e / (PD * PD);
  int rem = e - b * PD * PD;
  int i = rem / PD, j = rem - i * PD;
  float s = 0.f;
  for (int c = 0; c < CH; ++c) s += partial[((size_t)c * NB + b) * PD * PD + rem];
  float mui = S[b * PD + i] * INV_N, muj = S[b * PD + j] * INV_N;
  G[e] = s * INV_N - mui * muj;
}

// ---------------- Householder tridiagonalization (v16, unchanged) ----------------
__global__ __launch_bounds__(768, 3) void eigen_k(const float* __restrict__ sigma,
                                                  float* __restrict__ DDg,
                                                  float* __restrict__ EEg) {
  __shared__ float ppt[PD][20];     // transposed partials; cols 0..11 used (swizzled)
  __shared__ float vvg[2][PD];      // v, double-buffered by step parity, zero-padded
  __shared__ float wvg[PD];         // w values (each wave publishes its own window)
  __shared__ float red0[2];         // beta per parity
  __shared__ float red2[16];        // per-wave v^T A v partials (12 used + 4 zeros)
  __shared__ float dd[PD], ee[PD];

  int b = blockIdx.x, t = threadIdx.x;
  int w = t >> 6, l = t & 63;
  int colbase = w << 4;
  const float* M = sigma + (size_t)b * PD * PD;

  // load fragment (strided f4 global reads; matrix is L2-resident)
  f4 a[3][4];
#pragma unroll
  for (int rr = 0; rr < 3; ++rr) {
    const float* mp = M + (size_t)((rr << 6) + l) * PD + colbase;
#pragma unroll
    for (int cc = 0; cc < 4; ++cc)
      a[rr][cc] = *(const f4*)(mp + (cc << 2));
  }
  if (t >= 12 && t < 16) red2[t] = 0.f;

  // swizzled ppt column for this wave (depends on l only; same for all 3 rows)
  int swc = w + (l >> 3);
  if (swc >= 12) swc -= 12;

  // extract column c of this wave's slice into av[3] (compile-time indices)
  auto extract = [&](int c, float* av) {
#pragma unroll
    for (int cc = 0; cc < 4; ++cc)
#pragma unroll
      for (int e = 0; e < 4; ++e)
        if (colbase + (cc << 2) + e == c) {      // wave-uniform guard
          av[0] = a[0][cc][e]; av[1] = a[1][cc][e]; av[2] = a[2][cc][e];
        }
  };

  // prep_core(c, av): owner wave computes alpha/beta from column values av,
  // writes v into vvg[c&1] (zeros below head), ee[c], red0[c&1]. Caller guards.
  auto prep_core = [&](int c, float av0, float av1, float av2) {
    int k1 = c + 1;
    float am0 = (l >= k1) ? av0 : 0.f;           // row0 = l
    float am1 = (l + 64 >= k1) ? av1 : 0.f;
    float am2 = (l + 128 >= k1) ? av2 : 0.f;
    float sq = wave_sum(am0 * am0 + am1 * am1 + am2 * am2);
    int slot2 = k1 >> 6;                         // uniform
    float tmp = (slot2 == 0) ? av0 : (slot2 == 1) ? av1 : av2;
    float x0 = rdlane(tmp, k1 & 63);
    float nrm = __builtin_amdgcn_sqrtf(sq);
    float alpha = (x0 >= 0.f) ? -nrm : nrm;
    bool degen = (sq < 1e-32f);
    float beta = degen ? 0.f : __builtin_amdgcn_rcpf(sq - alpha * x0);
    if (l == 0) {
      red0[c & 1] = beta;
      ee[c] = degen ? x0 : alpha;
    }
    float head = x0 - alpha;
    vvg[c & 1][l]       = (l       < k1) ? 0.f : (l       == k1) ? head : am0;
    vvg[c & 1][l + 64]  = (l + 64  < k1) ? 0.f : (l + 64  == k1) ? head : am1;
    vvg[c & 1][l + 128] = (l + 128 < k1) ? 0.f : (l + 128 == k1) ? head : am2;
  };

  if (w == 0) {
    float av[3] = {0.f, 0.f, 0.f};
    extract(0, av);
    prep_core(0, av[0], av[1], av[2]);
  }
  __syncthreads();

  for (int k = 0; k < PD - 2; ++k) {
    int cur = k & 1;
    int k1 = k + 1;
    bool wact = (colbase + 15) >= k1;           // wave-uniform col retirement

    float vr[3] = {0.f, 0.f, 0.f};
    f4 sv4[4];

    // ---- Phase A: ppt[row][swz(w)] = A_slice_row . v; red2[w] partial ----
    if (wact) {
      vr[0] = vvg[cur][l]; vr[1] = vvg[cur][l + 64]; vr[2] = vvg[cur][l + 128];
#pragma unroll
      for (int cc = 0; cc < 4; ++cc)
        sv4[cc] = *(const f4*)&vvg[cur][colbase + (cc << 2)];   // broadcast b128
      float dp = 0.f;
#pragma unroll
      for (int rr = 0; rr < 3; ++rr) {
        if ((rr << 6) + 63 >= k1) {              // row-block retirement
          f4 s4 = sv4[0] * a[rr][0] + sv4[1] * a[rr][1]
                + sv4[2] * a[rr][2] + sv4[3] * a[rr][3];
          float s = (s4.x + s4.y) + (s4.z + s4.w);
          ppt[(rr << 6) + l][swc] = s;
          dp += vr[rr] * s;
        }
      }
      float dpt = wave_sum(dp);
      if (l == 0) red2[w] = dpt;
    } else if (k1 == colbase + 16) {             // one-time retirement cleanup
      ppt[l][swc] = 0.f; ppt[l + 64][swc] = 0.f; ppt[l + 128][swc] = 0.f;
      if (l == 0) red2[w] = 0.f;
    }
    __syncthreads();                             // B1

    // ---- Phase BC (fused): w own 3 rows, windowed publish, prep, update ----
    if (wact) {
      float rv = red2[l & 15];
      float vt = row16_sum(rv);                  // scalar v^T A v
      float beta = red0[cur];
      float Kc = 0.5f * beta * beta * vt;
      float wr[3] = {0.f, 0.f, 0.f};
#pragma unroll
      for (int rr = 0; rr < 3; ++rr) {
        if ((rr << 6) + 63 >= k1) {
          int row = (rr << 6) + l;
          f4 q = *(const f4*)&ppt[row][0];
          f4 q1 = *(const f4*)&ppt[row][4];
          f4 q2 = *(const f4*)&ppt[row][8];
          q += q1 + q2;
          float p = (q.x + q.y) + (q.z + q.w);
          wr[rr] = (row >= k1) ? (beta * p - Kc * vr[rr]) : 0.f;
          if (rr == (w >> 2)) {                  // wave-uniform rr guard
            if ((l >> 4) == (w & 3))             // window rows only
              wvg[row] = wr[rr];
          }
        }
      }
      // owner: pre-corrected column k+1 -> prep between publish and sw4 read
      int cn = k + 1;
      if (w == (cn >> 4)) {
        float av[3] = {0.f, 0.f, 0.f};
        extract(cn, av);
        float svv = vvg[cur][cn];                // broadcast
        float swv = wvg[cn];                     // broadcast (this wave wrote it)
#pragma unroll
        for (int rr = 0; rr < 3; ++rr) av[rr] -= vr[rr] * swv + wr[rr] * svv;
        prep_core(cn, av[0], av[1], av[2]);
      }
      f4 sw4[4];
#pragma unroll
      for (int cc = 0; cc < 4; ++cc)
        sw4[cc] = *(const f4*)&wvg[colbase + (cc << 2)];   // own window, same wave
      // rank-2 update (f4 math)
#pragma unroll
      for (int rr = 0; rr < 3; ++rr) {
        if ((rr << 6) + 63 >= k1) {
          float vrr = vr[rr], wrr = wr[rr];
#pragma unroll
          for (int cc = 0; cc < 4; ++cc)
            a[rr][cc] -= sw4[cc] * vrr + sv4[cc] * wrr;
        }
      }
    }
    __syncthreads();                             // B2
  }

  // ---- extract diagonal, write dd/ee to workspace ----
#pragma unroll
  for (int rr = 0; rr < 3; ++rr) {
    int row = (rr << 6) + l;
#pragma unroll
    for (int cc = 0; cc < 4; ++cc)
#pragma unroll
      for (int e = 0; e < 4; ++e)
        if (colbase + (cc << 2) + e == row) dd[row] = a[rr][cc][e];
  }
  __syncthreads();
  if (t < PD) {
    DDg[b * PD + t] = dd[t];
    EEg[b * PD + t] = (t < PD - 1) ? ee[t] : 0.f;
  }
}

// ---------------- 5-ary Sturm bisection via 3-term char-poly recurrence ----------------
__global__ __launch_bounds__(192) void bisect_k(const float* __restrict__ DDg,
                                                const float* __restrict__ EEg,
                                                float* __restrict__ SIGg) {
  __shared__ float dd[PD], e2[PD];
  __shared__ float grd[8];
  __shared__ int   cntb[4][48];

  int blk = blockIdx.x;
  int b = blk >> 2, q = blk & 3;
  int t = threadIdx.x;
  int w = t >> 6, l = t & 63;

  float eept = EEg[b * PD + t];
  dd[t] = DDg[b * PD + t];
  e2[t] = eept * eept;
  __syncthreads();

  // Gershgorin bounds over the full spectrum
  float glo, ghi;
  {
    float r = fabsf(eept);
    if (t > 0) r += sqrtf(e2[t - 1]);
    glo = dd[t] - r;
    ghi = dd[t] + r;
  }
#pragma unroll
  for (int off = 32; off; off >>= 1) {
    glo = fminf(glo, __shfl_xor(glo, off, 64));
    ghi = fmaxf(ghi, __shfl_xor(ghi, off, 64));
  }
  if (l == 0) { grd[w] = glo; grd[4 + w] = ghi; }
  __syncthreads();
  float gl = fminf(grd[0], fminf(grd[1], grd[2]));
  float gh = fmaxf(grd[4], fmaxf(grd[5], grd[6]));
  float wid = gh - gl;
  gl -= 1e-3f * wid + 1e-20f;
  gh += 1e-3f * wid + 1e-20f;

  // 4 probe threads per eigenvalue; this block handles eigs [48q, 48q+48)
  int sub = t / 48;                 // 0..3
  int el = t - sub * 48;
  int e = q * 48 + el;
  float lo = gl, hi = gh;
  for (int round = 0; round < 8; ++round) {
    float width = hi - lo;
    float xm = lo + width * (0.2f * (float)(sub + 1));
    // Sturm count via p-recurrence
    float p0 = 1.f, p1 = dd[0] - xm;
    int cnt = (int)(__float_as_uint(p1) >> 31);
    // 47 blocks of 4 (i = 1..188), rescale each block
    for (int i = 1; i < 189; i += 4) {
#pragma unroll
      for (int j = 0; j < 4; ++j) {
        int idx = i + j;
        float p2 = (dd[idx] - xm) * p1 - e2[idx - 1] * p0;
        cnt += (int)((__float_as_uint(p2) ^ __float_as_uint(p1)) >> 31);
        p0 = p1; p1 = p2;
      }
      float ap = fabsf(p1);
      float s = (ap > 1e12f) ? 1e-12f : ((ap < 1e-12f) ? 1e12f : 1.0f);
      p1 *= s; p0 *= s;
    }
    // tail: idx = 189,190,191
#pragma unroll
    for (int idx = 189; idx < PD; ++idx) {
      float p2 = (dd[idx] - xm) * p1 - e2[idx - 1] * p0;
      cnt += (int)((__float_as_uint(p2) ^ __float_as_uint(p1)) >> 31);
      p0 = p1; p1 = p2;
    }
    cntb[sub][el] = cnt;
    __syncthreads();
    int c0 = cntb[0][el], c1 = cntb[1][el], c2 = cntb[2][el], c3 = cntb[3][el];
    float mA = lo + width * 0.2f, mB = lo + width * 0.4f;
    float mC = lo + width * 0.6f, mD = lo + width * 0.8f;
    float nl = lo, nh = hi;
    if (c0 <= e) nl = mA;
    if (c1 <= e) nl = mB;
    if (c2 <= e) nl = mC;
    if (c3 <= e) nl = mD;
    if (c3 > e) nh = mD;
    if (c2 > e) nh = mC;
    if (c1 > e) nh = mB;
    if (c0 > e) nh = mA;
    lo = nl; hi = nh;
    __syncthreads();
  }
  if (sub == 0) SIGg[b * PD + e] = 0.5f * (lo + hi);
}

// ---------------- scan + threshold search + output ----------------
__global__ __launch_bounds__(192) void final_k(const float* __restrict__ SIGg,
                                               float* __restrict__ out) {
  __shared__ float sig[PD], csum[PD];
  __shared__ float scanw[4];
  __shared__ int   redi[4];

  int b = blockIdx.x, t = threadIdx.x;
  int w = t >> 6, l = t & 63;

  sig[t] = SIGg[b * PD + t];
  __syncthreads();

  // parallel inclusive scan of sig -> csum
  {
    float scn = sig[t];
#pragma unroll
    for (int off = 1; off < 64; off <<= 1) {
      float u = __shfl_up(scn, off, 64);
      if (l >= off) scn += u;
    }
    if (l == 63) scanw[w] = scn;
    __syncthreads();
    float base = 0.f;
    if (w >= 1) base += scanw[0];
    if (w >= 2) base += scanw[1];
    csum[t] = scn + base;
  }
  __syncthreads();

  // threshold search (mirror of the reference's vectorized loop)
  float tau = 0.f;
  int vk = 1 << 30;
  {
    int L = PD - 1 - t;
    tau = (L > 0) ? csum[L - 1] / (float)L : 0.0f;
    int gt = 0, lt2 = 0;
    for (int j = 0; j < L; ++j) {
      float svv = sig[j];
      gt  += (svv > tau);
      lt2 += (svv < tau);
    }
    if (gt == lt2) vk = t;
  }
#pragma unroll
  for (int off = 32; off; off >>= 1) vk = min(vk, __shfl_xor(vk, off, 64));
  if (l == 0) redi[w] = vk;
  __syncthreads();
  if (t == 0) {
    int g = min(redi[0], min(redi[1], redi[2]));
    redi[3] = (g == (1 << 30)) ? 0 : g;   // reference: argmax of all-false = 0
  }
  __syncthreads();
  if (t == redi[3]) out[b] = sqrtf(fmaxf(tau, 0.f));
}

extern "C" void kernel_launch(void* const* d_in, const int* in_sizes, int n_in,
                              void* d_out, int out_size, void* d_ws, size_t ws_size,
                              hipStream_t stream) {
  const float* x = (const float*)d_in[0];
  float* out = (float*)d_out;

  size_t gElems = (size_t)NB * PD * PD;       // 294912
  int CH = 64;   // 512 blocks = 2/CU -> 4 waves/SIMD for the latency-bound staging
  while (CH > 1 &&
         ws_size < ((size_t)CH + 1) * gElems * 4 + (size_t)NB * PD * 4 +
                   (size_t)CH * NB * PD * 4 + 3 * (size_t)NB * PD * 4)
    CH >>= 1;
  float* G = (float*)d_ws;
  float* partial = G + gElems;
  float* S = partial + (size_t)CH * gElems;
  float* Spart = S + (size_t)NB * PD;
  float* DDg = Spart + (size_t)CH * NB * PD;
  float* EEg = DDg + (size_t)NB * PD;
  float* SIGg = EEg + (size_t)NB * PD;
  int chunkSize = (NPATCH + CH - 1) / CH;

  cov_gemm_k<<<NB * CH, 512, 0, stream>>>(x, partial, Spart, CH, chunkSize);
  musum_k<<<NB, 192, 0, stream>>>(Spart, S, CH);
  reduce_fin_k<<<(int)((gElems + 255) / 256), 256, 0, stream>>>(partial, S, G, CH);
  eigen_k<<<NB, 768, 0, stream>>>(G, DDg, EEg);
  bisect_k<<<NB * 4, 192, 0, stream>>>(DDg, EEg, SIGg);
  final_k<<<NB, 192, 0, stream>>>(SIGg, out);
}

// Round 19
// 419.868 us; speedup vs baseline: 1.0536x; 1.0536x over previous
//
#include <hip/hip_runtime.h>
#include <math.h>

#define NB 8          // batch
#define NC 3          // channels
#define PD 192        // feature dim = 3*8*8
#define IMG 512
#define NP 169        // patches per spatial dim
#define NPATCH 28561  // NP*NP
#define INV_N (1.0f/28561.0f)
#define KST 32        // GEMM K-step (patches per MFMA tile)

typedef float f4 __attribute__((ext_vector_type(4)));
typedef __bf16 bf16x8 __attribute__((ext_vector_type(8)));
typedef float f32x4 __attribute__((ext_vector_type(4)));

__device__ __forceinline__ float rdlane(float v, int lane) {
  return __uint_as_float(__builtin_amdgcn_readlane(__float_as_uint(v), lane));
}

// DPP-based add of a shifted copy (VALU, no LDS pipe).
template<int CTRL, int RM, int BM>
__device__ __forceinline__ float dpp_add(float x) {
  int sh = __builtin_amdgcn_update_dpp(0, __float_as_int(x), CTRL, RM, BM, false);
  return x + __int_as_float(sh);
}
// sum over all 64 lanes -> scalar (uniform)
__device__ __forceinline__ float wave_sum(float x) {
  x = dpp_add<0x111, 0xF, 0xF>(x);   // row_shr:1
  x = dpp_add<0x112, 0xF, 0xF>(x);   // row_shr:2
  x = dpp_add<0x114, 0xF, 0xF>(x);   // row_shr:4
  x = dpp_add<0x118, 0xF, 0xF>(x);   // row_shr:8
  x = dpp_add<0x142, 0xA, 0xF>(x);   // row_bcast:15 -> rows 1,3
  x = dpp_add<0x143, 0xC, 0xF>(x);   // row_bcast:31 -> rows 2,3
  return rdlane(x, 63);
}
// sum over lanes 0..15 (replicated per 16-group) -> scalar
__device__ __forceinline__ float row16_sum(float x) {
  x = dpp_add<0x111, 0xF, 0xF>(x);
  x = dpp_add<0x112, 0xF, 0xF>(x);
  x = dpp_add<0x114, 0xF, 0xF>(x);
  x = dpp_add<0x118, 0xF, 0xF>(x);
  return rdlane(x, 15);
}

// RNE float->bf16 bits
__device__ __forceinline__ unsigned bfh(float v) {
  unsigned u = __float_as_uint(v);
  return (u + 0x7FFFu + ((u >> 16) & 1u)) >> 16;
}

// ---------------- split-K Gram via bf16-split MFMA + fused feature sums ----------------
__global__ __launch_bounds__(512) void cov_gemm_k(const float* __restrict__ x,
                                                  float* __restrict__ partial,
                                                  float* __restrict__ Spart,
                                                  int CH, int chunkSize) {
  int chunk = blockIdx.x % CH;
  int b = blockIdx.x / CH;
  int p0 = chunk * chunkSize;
  int pcount = NPATCH - p0;
  if (pcount > chunkSize) pcount = chunkSize;
  if (pcount < 0) pcount = 0;
  int nkt = (pcount + KST - 1) / KST;
  int pend = p0 + pcount;

  __shared__ unsigned short hiT[PD * 40];   // row stride 40 ushorts = 80B
  __shared__ unsigned short loT[PD * 40];
  __shared__ float sred[PD * 16];           // feature-sum reduce buffer

  int t = threadIdx.x;
  int l = t & 63, w = t >> 6;
  int wr = w >> 2, wc = w & 3;
  int m0 = wr * 96, n0 = wc * 48;
  const float* imgb = x + (size_t)b * NC * IMG * IMG;

  f32x4 acc[6][3];
#pragma unroll
  for (int i = 0; i < 6; ++i)
#pragma unroll
    for (int j = 0; j < 3; ++j)
      acc[i][j] = (f32x4){0.f, 0.f, 0.f, 0.f};

  float fsum[6] = {0.f, 0.f, 0.f, 0.f, 0.f, 0.f};

  int krow = (l >> 4) << 3;   // ushort k-offset: 0,8,16,24
  int rsel = l & 15;

  for (int kt = 0; kt < nkt; ++kt) {
    int pbase = p0 + kt * KST;
#pragma unroll
    for (int s = 0; s < 6; ++s) {
      int idx = (s << 9) + t;          // 0..3071
      int f = idx >> 4, p2 = idx & 15;
      int c = f >> 6, ii = (f >> 3) & 7, jj = f & 7;
      const float* imgc = imgb + (size_t)c * IMG * IMG;
      int P0 = pbase + (p2 << 1);
      float v0 = 0.f, v1 = 0.f;
      if (P0 < pend) { int ph = P0 / NP, pw = P0 - ph * NP; v0 = imgc[(3 * ph + ii) * IMG + 3 * pw + jj]; }
      if (P0 + 1 < pend) { int ph = (P0 + 1) / NP, pw = (P0 + 1) - ph * NP; v1 = imgc[(3 * ph + ii) * IMG + 3 * pw + jj]; }
      fsum[s] += v0 + v1;
      unsigned h0 = bfh(v0), h1 = bfh(v1);
      float r0 = v0 - __uint_as_float(h0 << 16);
      float r1 = v1 - __uint_as_float(h1 << 16);
      unsigned g0 = bfh(r0), g1 = bfh(r1);
      *(unsigned*)&hiT[f * 40 + (p2 << 1)] = h0 | (h1 << 16);
      *(unsigned*)&loT[f * 40 + (p2 << 1)] = g0 | (g1 << 16);
    }
    __syncthreads();

    bf16x8 ah[6], al[6], bh[3], bl[3];
#pragma unroll
    for (int i = 0; i < 6; ++i) {
      int row = m0 + i * 16 + rsel;
      ah[i] = *(const bf16x8*)&hiT[row * 40 + krow];
      al[i] = *(const bf16x8*)&loT[row * 40 + krow];
    }
#pragma unroll
    for (int j = 0; j < 3; ++j) {
      int row = n0 + j * 16 + rsel;
      bh[j] = *(const bf16x8*)&hiT[row * 40 + krow];
      bl[j] = *(const bf16x8*)&loT[row * 40 + krow];
    }
#pragma unroll
    for (int i = 0; i < 6; ++i)
#pragma unroll
      for (int j = 0; j < 3; ++j) {
        acc[i][j] = __builtin_amdgcn_mfma_f32_16x16x32_bf16(ah[i], bh[j], acc[i][j], 0, 0, 0);
        acc[i][j] = __builtin_amdgcn_mfma_f32_16x16x32_bf16(ah[i], bl[j], acc[i][j], 0, 0, 0);
        acc[i][j] = __builtin_amdgcn_mfma_f32_16x16x32_bf16(al[i], bh[j], acc[i][j], 0, 0, 0);
      }
    __syncthreads();
  }

  // ---- feature-sum reduce: sred[f][p2] -> Spart ----
#pragma unroll
  for (int s = 0; s < 6; ++s) {
    int f = (t >> 4) + (s << 5);
    sred[(f << 4) | (t & 15)] = fsum[s];
  }
  __syncthreads();
  if (t < PD) {
    float s = 0.f;
#pragma unroll
    for (int p2 = 0; p2 < 16; ++p2) s += sred[(t << 4) | p2];
    Spart[((size_t)chunk * NB + b) * PD + t] = s;
  }

  float* outp = partial + ((size_t)chunk * NB + b) * PD * PD;
#pragma unroll
  for (int i = 0; i < 6; ++i) {
    int rowb = m0 + i * 16 + ((l >> 4) << 2);
#pragma unroll
    for (int r = 0; r < 4; ++r)
#pragma unroll
      for (int j = 0; j < 3; ++j)
        outp[(size_t)(rowb + r) * PD + n0 + j * 16 + (l & 15)] = acc[i][j][r];
  }
}

// ---------------- sum per-chunk feature sums -> S ----------------
__global__ __launch_bounds__(192) void musum_k(const float* __restrict__ Spart,
                                               float* __restrict__ S, int CH) {
  int b = blockIdx.x, t = threadIdx.x;
  float s = 0.f;
  for (int c = 0; c < CH; ++c) s += Spart[((size_t)c * NB + b) * PD + t];
  S[b * PD + t] = s;
}

// ---------------- reduce partials + finalize covariance ----------------
__global__ __launch_bounds__(256) void reduce_fin_k(const float* __restrict__ partial,
                                                    const float* __restrict__ S,
                                                    float* __restrict__ G, int CH) {
  int e = blockIdx.x * 256 + threadIdx.x;
  const int tot = NB * PD * PD;
  if (e >= tot) return;
  int b = e / (PD * PD);
  int rem = e - b * PD * PD;
  int i = rem / PD, j = rem - i * PD;
  float s = 0.f;
  for (int c = 0; c < CH; ++c) s += partial[((size_t)c * NB + b) * PD * PD + rem];
  float mui = S[b * PD + i] * INV_N, muj = S[b * PD + j] * INV_N;
  G[e] = s * INV_N - mui * muj;
}

// ---------------- Householder tridiagonalization (v16, unchanged) ----------------
__global__ __launch_bounds__(768, 3) void eigen_k(const float* __restrict__ sigma,
                                                  float* __restrict__ DDg,
                                                  float* __restrict__ EEg) {
  __shared__ float ppt[PD][20];     // transposed partials; cols 0..11 used (swizzled)
  __shared__ float vvg[2][PD];      // v, double-buffered by step parity, zero-padded
  __shared__ float wvg[PD];         // w values (each wave publishes its own window)
  __shared__ float red0[2];         // beta per parity
  __shared__ float red2[16];        // per-wave v^T A v partials (12 used + 4 zeros)
  __shared__ float dd[PD], ee[PD];

  int b = blockIdx.x, t = threadIdx.x;
  int w = t >> 6, l = t & 63;
  int colbase = w << 4;
  const float* M = sigma + (size_t)b * PD * PD;

  // load fragment (strided f4 global reads; matrix is L2-resident)
  f4 a[3][4];
#pragma unroll
  for (int rr = 0; rr < 3; ++rr) {
    const float* mp = M + (size_t)((rr << 6) + l) * PD + colbase;
#pragma unroll
    for (int cc = 0; cc < 4; ++cc)
      a[rr][cc] = *(const f4*)(mp + (cc << 2));
  }
  if (t >= 12 && t < 16) red2[t] = 0.f;

  // swizzled ppt column for this wave (depends on l only; same for all 3 rows)
  int swc = w + (l >> 3);
  if (swc >= 12) swc -= 12;

  // extract column c of this wave's slice into av[3] (compile-time indices)
  auto extract = [&](int c, float* av) {
#pragma unroll
    for (int cc = 0; cc < 4; ++cc)
#pragma unroll
      for (int e = 0; e < 4; ++e)
        if (colbase + (cc << 2) + e == c) {      // wave-uniform guard
          av[0] = a[0][cc][e]; av[1] = a[1][cc][e]; av[2] = a[2][cc][e];
        }
  };

  // prep_core(c, av): owner wave computes alpha/beta from column values av,
  // writes v into vvg[c&1] (zeros below head), ee[c], red0[c&1]. Caller guards.
  auto prep_core = [&](int c, float av0, float av1, float av2) {
    int k1 = c + 1;
    float am0 = (l >= k1) ? av0 : 0.f;           // row0 = l
    float am1 = (l + 64 >= k1) ? av1 : 0.f;
    float am2 = (l + 128 >= k1) ? av2 : 0.f;
    float sq = wave_sum(am0 * am0 + am1 * am1 + am2 * am2);
    int slot2 = k1 >> 6;                         // uniform
    float tmp = (slot2 == 0) ? av0 : (slot2 == 1) ? av1 : av2;
    float x0 = rdlane(tmp, k1 & 63);
    float nrm = __builtin_amdgcn_sqrtf(sq);
    float alpha = (x0 >= 0.f) ? -nrm : nrm;
    bool degen = (sq < 1e-32f);
    float beta = degen ? 0.f : __builtin_amdgcn_rcpf(sq - alpha * x0);
    if (l == 0) {
      red0[c & 1] = beta;
      ee[c] = degen ? x0 : alpha;
    }
    float head = x0 - alpha;
    vvg[c & 1][l]       = (l       < k1) ? 0.f : (l       == k1) ? head : am0;
    vvg[c & 1][l + 64]  = (l + 64  < k1) ? 0.f : (l + 64  == k1) ? head : am1;
    vvg[c & 1][l + 128] = (l + 128 < k1) ? 0.f : (l + 128 == k1) ? head : am2;
  };

  if (w == 0) {
    float av[3] = {0.f, 0.f, 0.f};
    extract(0, av);
    prep_core(0, av[0], av[1], av[2]);
  }
  __syncthreads();

  for (int k = 0; k < PD - 2; ++k) {
    int cur = k & 1;
    int k1 = k + 1;
    bool wact = (colbase + 15) >= k1;           // wave-uniform col retirement

    float vr[3] = {0.f, 0.f, 0.f};
    f4 sv4[4];

    // ---- Phase A: ppt[row][swz(w)] = A_slice_row . v; red2[w] partial ----
    if (wact) {
      vr[0] = vvg[cur][l]; vr[1] = vvg[cur][l + 64]; vr[2] = vvg[cur][l + 128];
#pragma unroll
      for (int cc = 0; cc < 4; ++cc)
        sv4[cc] = *(const f4*)&vvg[cur][colbase + (cc << 2)];   // broadcast b128
      float dp = 0.f;
#pragma unroll
      for (int rr = 0; rr < 3; ++rr) {
        if ((rr << 6) + 63 >= k1) {              // row-block retirement
          f4 s4 = sv4[0] * a[rr][0] + sv4[1] * a[rr][1]
                + sv4[2] * a[rr][2] + sv4[3] * a[rr][3];
          float s = (s4.x + s4.y) + (s4.z + s4.w);
          ppt[(rr << 6) + l][swc] = s;
          dp += vr[rr] * s;
        }
      }
      float dpt = wave_sum(dp);
      if (l == 0) red2[w] = dpt;
    } else if (k1 == colbase + 16) {             // one-time retirement cleanup
      ppt[l][swc] = 0.f; ppt[l + 64][swc] = 0.f; ppt[l + 128][swc] = 0.f;
      if (l == 0) red2[w] = 0.f;
    }
    __syncthreads();                             // B1

    // ---- Phase BC (fused): w own 3 rows, windowed publish, prep, update ----
    if (wact) {
      float rv = red2[l & 15];
      float vt = row16_sum(rv);                  // scalar v^T A v
      float beta = red0[cur];
      float Kc = 0.5f * beta * beta * vt;
      float wr[3] = {0.f, 0.f, 0.f};
#pragma unroll
      for (int rr = 0; rr < 3; ++rr) {
        if ((rr << 6) + 63 >= k1) {
          int row = (rr << 6) + l;
          f4 q = *(const f4*)&ppt[row][0];
          f4 q1 = *(const f4*)&ppt[row][4];
          f4 q2 = *(const f4*)&ppt[row][8];
          q += q1 + q2;
          float p = (q.x + q.y) + (q.z + q.w);
          wr[rr] = (row >= k1) ? (beta * p - Kc * vr[rr]) : 0.f;
          if (rr == (w >> 2)) {                  // wave-uniform rr guard
            if ((l >> 4) == (w & 3))             // window rows only
              wvg[row] = wr[rr];
          }
        }
      }
      // owner: pre-corrected column k+1 -> prep between publish and sw4 read
      int cn = k + 1;
      if (w == (cn >> 4)) {
        float av[3] = {0.f, 0.f, 0.f};
        extract(cn, av);
        float svv = vvg[cur][cn];                // broadcast
        float swv = wvg[cn];                     // broadcast (this wave wrote it)
#pragma unroll
        for (int rr = 0; rr < 3; ++rr) av[rr] -= vr[rr] * swv + wr[rr] * svv;
        prep_core(cn, av[0], av[1], av[2]);
      }
      f4 sw4[4];
#pragma unroll
      for (int cc = 0; cc < 4; ++cc)
        sw4[cc] = *(const f4*)&wvg[colbase + (cc << 2)];   // own window, same wave
      // rank-2 update (f4 math)
#pragma unroll
      for (int rr = 0; rr < 3; ++rr) {
        if ((rr << 6) + 63 >= k1) {
          float vrr = vr[rr], wrr = wr[rr];
#pragma unroll
          for (int cc = 0; cc < 4; ++cc)
            a[rr][cc] -= sw4[cc] * vrr + sv4[cc] * wrr;
        }
      }
    }
    __syncthreads();                             // B2
  }

  // ---- extract diagonal, write dd/ee to workspace ----
#pragma unroll
  for (int rr = 0; rr < 3; ++rr) {
    int row = (rr << 6) + l;
#pragma unroll
    for (int cc = 0; cc < 4; ++cc)
#pragma unroll
      for (int e = 0; e < 4; ++e)
        if (colbase + (cc << 2) + e == row) dd[row] = a[rr][cc][e];
  }
  __syncthreads();
  if (t < PD) {
    DDg[b * PD + t] = dd[t];
    EEg[b * PD + t] = (t < PD - 1) ? ee[t] : 0.f;
  }
}

// ---------------- 5-ary Sturm bisection via 3-term char-poly recurrence ----------------
__global__ __launch_bounds__(192) void bisect_k(const float* __restrict__ DDg,
                                                const float* __restrict__ EEg,
                                                float* __restrict__ SIGg) {
  __shared__ float dd[PD], e2[PD];
  __shared__ float grd[8];
  __shared__ int   cntb[4][48];

  int blk = blockIdx.x;
  int b = blk >> 2, q = blk & 3;
  int t = threadIdx.x;
  int w = t >> 6, l = t & 63;

  float eept = EEg[b * PD + t];
  dd[t] = DDg[b * PD + t];
  e2[t] = eept * eept;
  __syncthreads();

  // Gershgorin bounds over the full spectrum
  float glo, ghi;
  {
    float r = fabsf(eept);
    if (t > 0) r += sqrtf(e2[t - 1]);
    glo = dd[t] - r;
    ghi = dd[t] + r;
  }
#pragma unroll
  for (int off = 32; off; off >>= 1) {
    glo = fminf(glo, __shfl_xor(glo, off, 64));
    ghi = fmaxf(ghi, __shfl_xor(ghi, off, 64));
  }
  if (l == 0) { grd[w] = glo; grd[4 + w] = ghi; }
  __syncthreads();
  float gl = fminf(grd[0], fminf(grd[1], grd[2]));
  float gh = fmaxf(grd[4], fmaxf(grd[5], grd[6]));
  float wid = gh - gl;
  gl -= 1e-3f * wid + 1e-20f;
  gh += 1e-3f * wid + 1e-20f;

  // 4 probe threads per eigenvalue; this block handles eigs [48q, 48q+48)
  int sub = t / 48;                 // 0..3
  int el = t - sub * 48;
  int e = q * 48 + el;
  float lo = gl, hi = gh;
  for (int round = 0; round < 8; ++round) {
    float width = hi - lo;
    float xm = lo + width * (0.2f * (float)(sub + 1));
    // Sturm count via p-recurrence
    float p0 = 1.f, p1 = dd[0] - xm;
    int cnt = (int)(__float_as_uint(p1) >> 31);
    // 47 blocks of 4 (i = 1..188), rescale each block
    for (int i = 1; i < 189; i += 4) {
#pragma unroll
      for (int j = 0; j < 4; ++j) {
        int idx = i + j;
        float p2 = (dd[idx] - xm) * p1 - e2[idx - 1] * p0;
        cnt += (int)((__float_as_uint(p2) ^ __float_as_uint(p1)) >> 31);
        p0 = p1; p1 = p2;
      }
      float ap = fabsf(p1);
      float s = (ap > 1e12f) ? 1e-12f : ((ap < 1e-12f) ? 1e12f : 1.0f);
      p1 *= s; p0 *= s;
    }
    // tail: idx = 189,190,191
#pragma unroll
    for (int idx = 189; idx < PD; ++idx) {
      float p2 = (dd[idx] - xm) * p1 - e2[idx - 1] * p0;
      cnt += (int)((__float_as_uint(p2) ^ __float_as_uint(p1)) >> 31);
      p0 = p1; p1 = p2;
    }
    cntb[sub][el] = cnt;
    __syncthreads();
    int c0 = cntb[0][el], c1 = cntb[1][el], c2 = cntb[2][el], c3 = cntb[3][el];
    float mA = lo + width * 0.2f, mB = lo + width * 0.4f;
    float mC = lo + width * 0.6f, mD = lo + width * 0.8f;
    float nl = lo, nh = hi;
    if (c0 <= e) nl = mA;
    if (c1 <= e) nl = mB;
    if (c2 <= e) nl = mC;
    if (c3 <= e) nl = mD;
    if (c3 > e) nh = mD;
    if (c2 > e) nh = mC;
    if (c1 > e) nh = mB;
    if (c0 > e) nh = mA;
    lo = nl; hi = nh;
    __syncthreads();
  }
  if (sub == 0) SIGg[b * PD + e] = 0.5f * (lo + hi);
}

// ---------------- scan + threshold search + output ----------------
__global__ __launch_bounds__(192) void final_k(const float* __restrict__ SIGg,
                                               float* __restrict__ out) {
  __shared__ float sig[PD], csum[PD];
  __shared__ float scanw[4];
  __shared__ int   redi[4];

  int b = blockIdx.x, t = threadIdx.x;
  int w = t >> 6, l = t & 63;

  sig[t] = SIGg[b * PD + t];
  __syncthreads();

  // parallel inclusive scan of sig -> csum
  {
    float scn = sig[t];
#pragma unroll
    for (int off = 1; off < 64; off <<= 1) {
      float u = __shfl_up(scn, off, 64);
      if (l >= off) scn += u;
    }
    if (l == 63) scanw[w] = scn;
    __syncthreads();
    float base = 0.f;
    if (w >= 1) base += scanw[0];
    if (w >= 2) base += scanw[1];
    csum[t] = scn + base;
  }
  __syncthreads();

  // threshold search (mirror of the reference's vectorized loop)
  float tau = 0.f;
  int vk = 1 << 30;
  {
    int L = PD - 1 - t;
    tau = (L > 0) ? csum[L - 1] / (float)L : 0.0f;
    int gt = 0, lt2 = 0;
    for (int j = 0; j < L; ++j) {
      float svv = sig[j];
      gt  += (svv > tau);
      lt2 += (svv < tau);
    }
    if (gt == lt2) vk = t;
  }
#pragma unroll
  for (int off = 32; off; off >>= 1) vk = min(vk, __shfl_xor(vk, off, 64));
  if (l == 0) redi[w] = vk;
  __syncthreads();
  if (t == 0) {
    int g = min(redi[0], min(redi[1], redi[2]));
    redi[3] = (g == (1 << 30)) ? 0 : g;   // reference: argmax of all-false = 0
  }
  __syncthreads();
  if (t == redi[3]) out[b] = sqrtf(fmaxf(tau, 0.f));
}

extern "C" void kernel_launch(void* const* d_in, const int* in_sizes, int n_in,
                              void* d_out, int out_size, void* d_ws, size_t ws_size,
                              hipStream_t stream) {
  const float* x = (const float*)d_in[0];
  float* out = (float*)d_out;

  size_t gElems = (size_t)NB * PD * PD;       // 294912
  int CH = 32;   // measured optimum (CH=64 regressed: doubled partial traffic)
  while (CH > 1 &&
         ws_size < ((size_t)CH + 1) * gElems * 4 + (size_t)NB * PD * 4 +
                   (size_t)CH * NB * PD * 4 + 3 * (size_t)NB * PD * 4)
    CH >>= 1;
  float* G = (float*)d_ws;
  float* partial = G + gElems;
  float* S = partial + (size_t)CH * gElems;
  float* Spart = S + (size_t)NB * PD;
  float* DDg = Spart + (size_t)CH * NB * PD;
  float* EEg = DDg + (size_t)NB * PD;
  float* SIGg = EEg + (size_t)NB * PD;
  int chunkSize = (NPATCH + CH - 1) / CH;

  cov_gemm_k<<<NB * CH, 512, 0, stream>>>(x, partial, Spart, CH, chunkSize);
  musum_k<<<NB, 192, 0, stream>>>(Spart, S, CH);
  reduce_fin_k<<<(int)((gElems + 255) / 256), 256, 0, stream>>>(partial, S, G, CH);
  eigen_k<<<NB, 768, 0, stream>>>(G, DDg, EEg);
  bisect_k<<<NB * 4, 192, 0, stream>>>(DDg, EEg, SIGg);
  final_k<<<NB, 192, 0, stream>>>(SIGg, out);
}